// Round 8
// baseline (2489.208 us; speedup 1.0000x reference)
//
#include <hip/hip_runtime.h>

#define TSEQ 512

typedef unsigned short us8v __attribute__((ext_vector_type(8)));
typedef __bf16 bf16x8 __attribute__((ext_vector_type(8)));
typedef float f32x4 __attribute__((ext_vector_type(4)));
typedef unsigned u32x4 __attribute__((ext_vector_type(4)));

// ---- workspace layout (bytes) ----
#define OFF_BIAS  0u           // 2*2048 f32
#define OFF_X16   16384u       // x bf16 [512 t][64 b][64 d] = 4 MiB
#define OFF_W0    4210688u     // Wcat0 bf16 [2048][576]
#define OFF_W1    6569984u     // Wcat1 bf16 [2048][1024]
#define OFF_Y0P   10764288u    // y0 plain bf16 [512 t][4 bg][32 hg][16 b][16 p] = 32 MiB
#define OFF_RING0 44318720u    // L0 tagged ring [2 par][4 bg][32 hg][16 b][4 u][16B] = 256 KiB
#define OFF_RING1 44580864u    // L1 tagged ring, same shape = 256 KiB
#define OFF_HFIN  44843008u    // final h1 plain [4 bg][32 hg][16 b][16 p] = 64 KiB

static __device__ __forceinline__ unsigned short f2bf(float f) {
    unsigned u = __builtin_bit_cast(unsigned, f);
    u += 0x7fffu + ((u >> 16) & 1u);            // RNE
    return (unsigned short)(u >> 16);
}
static __device__ __forceinline__ float sigmf(float x) { return 1.0f / (1.0f + __expf(-x)); }
static __device__ __forceinline__ float tanh_fast(float x) {
    float a = fabsf(x);
    float e = __expf(-2.0f * a);
    float t = (1.0f - e) / (1.0f + e);
    return copysignf(t, x);
}
static __device__ __forceinline__ f32x4 mfma16(us8v a, us8v b, f32x4 c) {
    return __builtin_amdgcn_mfma_f32_16x16x32_bf16(
        __builtin_bit_cast(bf16x8, a), __builtin_bit_cast(bf16x8, b), c, 0, 0, 0);
}
static __device__ __forceinline__ bool fresh8(u32x4 a,u32x4 b,u32x4 c,u32x4 d,
                                              u32x4 e,u32x4 f,u32x4 g,u32x4 h,unsigned ep) {
    unsigned x = (a[3]^ep)|(b[3]^ep)|(c[3]^ep)|(d[3]^ep)|(e[3]^ep)|(f[3]^ep)|(g[3]^ep)|(h[3]^ep);
    return __all((int)(x == 0u));
}

// ---------------- setup: fp32 -> bf16 conversions + concatenated weights ----------------
__global__ void setup_kernel(const float* __restrict__ x,
                             const float* __restrict__ wih0, const float* __restrict__ whh0,
                             const float* __restrict__ bih0, const float* __restrict__ bhh0,
                             const float* __restrict__ wih1, const float* __restrict__ whh1,
                             const float* __restrict__ bih1, const float* __restrict__ bhh1,
                             char* __restrict__ ws)
{
    unsigned idx = blockIdx.x * blockDim.x + threadIdx.x;
    unsigned stride = gridDim.x * blockDim.x;
    unsigned short* x16 = (unsigned short*)(ws + OFF_X16);
    unsigned short* w0  = (unsigned short*)(ws + OFF_W0);
    unsigned short* w1  = (unsigned short*)(ws + OFF_W1);
    float* bias = (float*)(ws + OFF_BIAS);
    const unsigned NX  = 64u*512u*64u;
    const unsigned NW0 = 2048u*576u;
    const unsigned NW1 = 2048u*1024u;
    const unsigned NT  = NX + NW0 + NW1 + 4096u;
    for (unsigned i = idx; i < NT; i += stride) {
        if (i < NX) {
            unsigned d = i & 63u, b = (i >> 6) & 63u, t = i >> 12;
            x16[i] = f2bf(x[((b << 9) + t) * 64u + d]);
        } else if (i < NX + NW0) {
            unsigned k = i - NX; unsigned r = k / 576u, c = k % 576u;
            float v = (c < 64u) ? wih0[r*64u + c] : whh0[r*512u + (c - 64u)];
            w0[k] = f2bf(v);
        } else if (i < NX + NW0 + NW1) {
            unsigned k = i - NX - NW0; unsigned r = k >> 10, c = k & 1023u;
            float v = (c < 512u) ? wih1[(r<<9) + c] : whh1[(r<<9) + (c - 512u)];
            w1[k] = f2bf(v);
        } else {
            unsigned k = i - NX - NW0 - NW1;
            float v = (k < 2048u) ? (bih0[k] + bhh0[k]) : (bih1[k-2048u] + bhh1[k-2048u]);
            bias[k] = v;
        }
    }
}

// ---------------- persistent recurrence kernel ----------------
// 128 blocks = 4 bg x 32 hg. Epoch-tagged 16B exchange units {4 h, pad, epoch}
// stored/loaded by single dwordx4 (atomic unit). Producer's store IS the
// release; consumer polls exactly the units it consumes. Every asm load block
// is SELF-CONTAINED (issue + vmcnt(0) in one asm) so outputs are fully
// defined at asm exit -- no in-flight registers across asm boundaries.
__launch_bounds__(256, 1)
__global__ void lstm_persist(char* __restrict__ ws)
{
    const int tid  = threadIdx.x;
    const int kq   = tid >> 6;      // wave = K-quarter
    const int lane = tid & 63;
    const int l15  = lane & 15;     // B-frag batch row / D col
    const int lhi  = lane >> 4;     // k-sub / D row-group
    const int bg   = blockIdx.x & 3;
    const int hg   = blockIdx.x >> 2;

    const float* bias = (const float*)(ws + OFF_BIAS);
    const char*  x16  = ws + OFF_X16;
    char* y0p   = ws + OFF_Y0P;
    char* ring0 = ws + OFF_RING0;
    char* ring1 = ws + OFF_RING1;

    __shared__ __align__(16) char arena[86016];     // >80KB -> 1 block/CU
    float* gsum   = (float*)arena;                  // [2 par][64 rows][68]
    float* bias_l = (float*)(arena + 35840);        // 64 f32

    if (tid < 64) bias_l[tid] = bias[(tid >> 4)*512 + hg*16 + (tid & 15)];

    float cst = 0.0f;   // cell state: thread owns (b_ = tid>>4, p_ = tid&15)
    const int b_ = tid >> 4, p_ = tid & 15;

    us8v A[4][8];
    {
        const char* w0p = ws + OFF_W0;
        #pragma unroll
        for (int m = 0; m < 4; ++m) {
            const char* base = w0p + (size_t)(m*512 + hg*16 + l15)*1152 + lhi*16;
            #pragma unroll
            for (int kk = 0; kk < 4; ++kk)
                A[m][kk] = *(const us8v*)(base + (2 + kq*4 + kk)*64);   // h k-tiles
            if (kq < 2) A[m][4] = *(const us8v*)(base + kq*64);         // x k-tiles
        }
    }
    __syncthreads();

    // constant per-lane byte offsets
    const int vo_a   = kq*8192 + (lhi>>1)*1024 + l15*64 + (lhi&1)*32;  // tagged units (kk0/1)
    const int vo_b   = vo_a + 4096;                                    // (kk2/3)
    const int vo_x   = l15*128 + (kq & 1)*64 + lhi*16;                 // x frag (kq masked: valid for all waves)
    const int vo_y   = kq*4096 + (lhi>>1)*512 + l15*32 + (lhi&1)*16;   // y0 plain fragment
    const int vo_tag = b_*64 + (p_ & 3)*16;                            // producer tagged unit
    const int vo_pl  = b_*32 + (p_ & 1)*16;                            // producer plain half

    u32x4 c0,c1,c2,c3,c4,c5,c6,c7;   // poll data registers

// 8 tagged-unit loads + drain, one self-contained asm
#define LOAD8(SB)                                                               \
    asm volatile(                                                               \
        "global_load_dwordx4 %0, %8, %10 sc0 sc1\n\t"                           \
        "global_load_dwordx4 %1, %8, %10 offset:16 sc0 sc1\n\t"                 \
        "global_load_dwordx4 %2, %8, %10 offset:2048 sc0 sc1\n\t"               \
        "global_load_dwordx4 %3, %8, %10 offset:2064 sc0 sc1\n\t"               \
        "global_load_dwordx4 %4, %9, %10 sc0 sc1\n\t"                           \
        "global_load_dwordx4 %5, %9, %10 offset:16 sc0 sc1\n\t"                 \
        "global_load_dwordx4 %6, %9, %10 offset:2048 sc0 sc1\n\t"               \
        "global_load_dwordx4 %7, %9, %10 offset:2064 sc0 sc1\n\t"               \
        "s_waitcnt vmcnt(0)"                                                    \
        : "=&v"(c0),"=&v"(c1),"=&v"(c2),"=&v"(c3),                              \
          "=&v"(c4),"=&v"(c5),"=&v"(c6),"=&v"(c7)                               \
        : "v"(vo_a), "v"(vo_b), "s"(SB) : "memory")

// first poll iteration for layer 0: + x fragment (plain cached)
#define LOAD8X(SB, XR, SBX)                                                     \
    asm volatile(                                                               \
        "global_load_dwordx4 %8, %11, %12\n\t"                                  \
        "global_load_dwordx4 %0, %9, %13 sc0 sc1\n\t"                           \
        "global_load_dwordx4 %1, %9, %13 offset:16 sc0 sc1\n\t"                 \
        "global_load_dwordx4 %2, %9, %13 offset:2048 sc0 sc1\n\t"               \
        "global_load_dwordx4 %3, %9, %13 offset:2064 sc0 sc1\n\t"               \
        "global_load_dwordx4 %4, %10, %13 sc0 sc1\n\t"                          \
        "global_load_dwordx4 %5, %10, %13 offset:16 sc0 sc1\n\t"                \
        "global_load_dwordx4 %6, %10, %13 offset:2048 sc0 sc1\n\t"              \
        "global_load_dwordx4 %7, %10, %13 offset:2064 sc0 sc1\n\t"              \
        "s_waitcnt vmcnt(0)"                                                    \
        : "=&v"(c0),"=&v"(c1),"=&v"(c2),"=&v"(c3),                              \
          "=&v"(c4),"=&v"(c5),"=&v"(c6),"=&v"(c7), "=&v"(XR)                    \
        : "v"(vo_a), "v"(vo_b), "v"(vo_x), "s"(SBX), "s"(SB) : "memory")

// first poll iteration for layer 1: + 4 y0 fragments (plain cached)
#define LOAD8Y(SB, SBY)                                                         \
    asm volatile(                                                               \
        "global_load_dwordx4 %8, %14, %15\n\t"                                  \
        "global_load_dwordx4 %9, %14, %15 offset:1024\n\t"                      \
        "global_load_dwordx4 %10, %14, %15 offset:2048\n\t"                     \
        "global_load_dwordx4 %11, %14, %15 offset:3072\n\t"                     \
        "global_load_dwordx4 %0, %12, %16 sc0 sc1\n\t"                          \
        "global_load_dwordx4 %1, %12, %16 offset:16 sc0 sc1\n\t"                \
        "global_load_dwordx4 %2, %12, %16 offset:2048 sc0 sc1\n\t"              \
        "global_load_dwordx4 %3, %12, %16 offset:2064 sc0 sc1\n\t"              \
        "global_load_dwordx4 %4, %13, %16 sc0 sc1\n\t"                          \
        "global_load_dwordx4 %5, %13, %16 offset:16 sc0 sc1\n\t"                \
        "global_load_dwordx4 %6, %13, %16 offset:2048 sc0 sc1\n\t"              \
        "global_load_dwordx4 %7, %13, %16 offset:2064 sc0 sc1\n\t"              \
        "s_waitcnt vmcnt(0)"                                                    \
        : "=&v"(c0),"=&v"(c1),"=&v"(c2),"=&v"(c3),                              \
          "=&v"(c4),"=&v"(c5),"=&v"(c6),"=&v"(c7),                              \
          "=&v"(yr0),"=&v"(yr1),"=&v"(yr2),"=&v"(yr3)                           \
        : "v"(vo_a), "v"(vo_b), "v"(vo_y), "s"(SBY), "s"(SB) : "memory")

#define FRAG(a,b) __builtin_bit_cast(us8v, (u32x4){(a)[0],(a)[1],(b)[0],(b)[1]})

#define GSUM_WRITE(PAR)                                                           \
    do {                                                                          \
        float* gs_ = gsum + (PAR)*4352;                                           \
        _Pragma("unroll")                                                         \
        for (int m = 0; m < 4; ++m) {                                             \
            _Pragma("unroll")                                                     \
            for (int q = 0; q < 4; ++q)                                           \
                gs_[(m*16 + lhi*4 + q)*68 + kq*17 + l15] = acc[m][q];             \
        }                                                                         \
    } while (0)

#define ACT_STEP(PAR, EPS, SBTAG, DOPLAIN, SBPL)                                  \
    do {                                                                          \
        const float* gsr = gsum + (PAR)*4352;                                     \
        float g4[4];                                                              \
        _Pragma("unroll")                                                         \
        for (int g = 0; g < 4; ++g) {                                             \
            float s = bias_l[g*16 + p_];                                          \
            _Pragma("unroll")                                                     \
            for (int kk = 0; kk < 4; ++kk) s += gsr[(g*16 + p_)*68 + kk*17 + b_]; \
            g4[g] = s;                                                            \
        }                                                                         \
        float iv = sigmf(g4[0]), fv = sigmf(g4[1]);                               \
        float gv = tanh_fast(g4[2]), ov = sigmf(g4[3]);                           \
        cst = fv*cst + iv*gv;                                                     \
        float hh = ov * tanh_fast(cst);                                           \
        unsigned hv = f2bf(hh);                                                   \
        unsigned pk = (hv & 0xffffu) | (((unsigned)__shfl_xor((int)hv,1)) << 16); \
        int rbx = lane & 48;                                                      \
        unsigned Da = (unsigned)__shfl((int)pk, rbx + (p_&3)*4);                  \
        unsigned Db = (unsigned)__shfl((int)pk, rbx + (p_&3)*4 + 2);              \
        unsigned P0 = (unsigned)__shfl((int)pk, rbx + (p_&1)*8);                  \
        unsigned P1 = (unsigned)__shfl((int)pk, rbx + (p_&1)*8 + 2);              \
        unsigned P2 = (unsigned)__shfl((int)pk, rbx + (p_&1)*8 + 4);              \
        unsigned P3 = (unsigned)__shfl((int)pk, rbx + (p_&1)*8 + 6);              \
        if (p_ < 4) {                                                             \
            u32x4 tu = {Da, Db, 0u, (EPS)};                                       \
            asm volatile("global_store_dwordx4 %0, %1, %2 sc0 sc1"                \
                         :: "v"(vo_tag), "v"(tu), "s"(SBTAG) : "memory");         \
        }                                                                         \
        if ((DOPLAIN) && (p_ == 4 || p_ == 5)) {                                  \
            u32x4 pu = {P0, P1, P2, P3};                                          \
            asm volatile("global_store_dwordx4 %0, %1, %2 sc0 sc1"                \
                         :: "v"(vo_pl), "v"(pu), "s"(SBPL) : "memory");           \
        }                                                                         \
    } while (0)

    // ================= layer 0 : K = 576 = [x_t(64) | h0(512)] =================
    for (int t = 0; t < TSEQ; ++t) {
        const int par = t & 1;
        const char* sbx = x16 + (size_t)t*8192 + bg*2048;
        u32x4 xr;
        f32x4 acc[4] = {{0.f,0.f,0.f,0.f},{0.f,0.f,0.f,0.f},{0.f,0.f,0.f,0.f},{0.f,0.f,0.f,0.f}};
        if (t > 0) {
            const char* sbr = ring0 + ((size_t)((t-1)&1)*4 + bg)*32768;
            const unsigned ep = (unsigned)t;
            LOAD8X(sbr, xr, sbx);
            while (!fresh8(c0,c1,c2,c3,c4,c5,c6,c7, ep)) LOAD8(sbr);
            if (kq < 2) {
                #pragma unroll
                for (int m = 0; m < 4; ++m)
                    acc[m] = mfma16(A[m][4], __builtin_bit_cast(us8v, xr), acc[m]);
            }
            us8v h0 = FRAG(c0,c1), h1 = FRAG(c2,c3), h2 = FRAG(c4,c5), h3 = FRAG(c6,c7);
            #pragma unroll
            for (int m = 0; m < 4; ++m) acc[m] = mfma16(A[m][0], h0, acc[m]);
            #pragma unroll
            for (int m = 0; m < 4; ++m) acc[m] = mfma16(A[m][1], h1, acc[m]);
            #pragma unroll
            for (int m = 0; m < 4; ++m) acc[m] = mfma16(A[m][2], h2, acc[m]);
            #pragma unroll
            for (int m = 0; m < 4; ++m) acc[m] = mfma16(A[m][3], h3, acc[m]);
        } else {
            asm volatile("global_load_dwordx4 %0, %1, %2\n\ts_waitcnt vmcnt(0)"
                         : "=&v"(xr) : "v"(vo_x), "s"(sbx) : "memory");
            if (kq < 2) {
                #pragma unroll
                for (int m = 0; m < 4; ++m)
                    acc[m] = mfma16(A[m][4], __builtin_bit_cast(us8v, xr), acc[m]);
            }
        }
        GSUM_WRITE(par);
        __syncthreads();
        const char* sbt = ring0 + ((size_t)par*4 + bg)*32768 + hg*1024;
        const char* sbp = y0p + ((size_t)t*4 + bg)*16384 + hg*512;
        ACT_STEP(par, (unsigned)(t + 1), sbt, 1, sbp);
    }

    __syncthreads();   // protect bias_l reload vs slow siblings' ACT reads
    {   // ---- reload A + bias for layer 1 (K = 1024 = [y0(512) | h1(512)]) ----
        const char* w1p = ws + OFF_W1;
        #pragma unroll
        for (int m = 0; m < 4; ++m) {
            const char* base = w1p + (size_t)(m*512 + hg*16 + l15)*2048 + lhi*16;
            #pragma unroll
            for (int kk = 0; kk < 4; ++kk) {
                A[m][kk]     = *(const us8v*)(base + (kq*4 + kk)*64);        // y0 k-tiles
                A[m][kk + 4] = *(const us8v*)(base + (16 + kq*4 + kk)*64);   // h  k-tiles
            }
        }
    }
    if (tid < 64) bias_l[tid] = bias[2048 + (tid >> 4)*512 + hg*16 + (tid & 15)];
    __syncthreads();
    // cst carries over: layer1 initial c = layer0 final c (reference quirk)

    for (int t = 0; t < TSEQ; ++t) {
        const int par = t & 1;
        const char* sby = y0p + ((size_t)t*4 + bg)*16384;
        const char* sbr = (t == 0) ? (ring0 + ((size_t)1*4 + bg)*32768)
                                   : (ring1 + ((size_t)((t-1)&1)*4 + bg)*32768);
        const unsigned ep = (unsigned)(512 + t);
        u32x4 yr0, yr1, yr2, yr3;
        LOAD8Y(sbr, sby);
        while (!fresh8(c0,c1,c2,c3,c4,c5,c6,c7, ep)) LOAD8(sbr);

        f32x4 acc[4] = {{0.f,0.f,0.f,0.f},{0.f,0.f,0.f,0.f},{0.f,0.f,0.f,0.f},{0.f,0.f,0.f,0.f}};
        #pragma unroll
        for (int m = 0; m < 4; ++m) acc[m] = mfma16(A[m][0], __builtin_bit_cast(us8v, yr0), acc[m]);
        #pragma unroll
        for (int m = 0; m < 4; ++m) acc[m] = mfma16(A[m][1], __builtin_bit_cast(us8v, yr1), acc[m]);
        #pragma unroll
        for (int m = 0; m < 4; ++m) acc[m] = mfma16(A[m][2], __builtin_bit_cast(us8v, yr2), acc[m]);
        #pragma unroll
        for (int m = 0; m < 4; ++m) acc[m] = mfma16(A[m][3], __builtin_bit_cast(us8v, yr3), acc[m]);
        {
            us8v h0 = FRAG(c0,c1), h1 = FRAG(c2,c3), h2 = FRAG(c4,c5), h3 = FRAG(c6,c7);
            #pragma unroll
            for (int m = 0; m < 4; ++m) acc[m] = mfma16(A[m][4], h0, acc[m]);
            #pragma unroll
            for (int m = 0; m < 4; ++m) acc[m] = mfma16(A[m][5], h1, acc[m]);
            #pragma unroll
            for (int m = 0; m < 4; ++m) acc[m] = mfma16(A[m][6], h2, acc[m]);
            #pragma unroll
            for (int m = 0; m < 4; ++m) acc[m] = mfma16(A[m][7], h3, acc[m]);
        }
        GSUM_WRITE(par);
        __syncthreads();
        const char* sbt = ring1 + ((size_t)par*4 + bg)*32768 + hg*1024;
        const char* sbp = ws + OFF_HFIN + ((size_t)bg*32 + hg)*512;
        ACT_STEP(par, (unsigned)(513 + t), sbt, (t == 511), sbp);
    }
#undef LOAD8
#undef LOAD8X
#undef LOAD8Y
#undef FRAG
#undef GSUM_WRITE
#undef ACT_STEP
}

// ---------------- final projection: out = h1_final @ lin_w.T + lin_b ----------------
__global__ void final_linear(const char* __restrict__ ws,
                             const float* __restrict__ linw, const float* __restrict__ linb,
                             float* __restrict__ out)
{
    __shared__ float hrow[512];
    int b = blockIdx.x;        // global batch 0..63
    int o = threadIdx.x;       // 64 outputs
    int bg = b >> 4, bl = b & 15;
    const char* src = ws + OFF_HFIN + ((size_t)bg*32 + (o >> 1))*512 + bl*32 + (o & 1)*16;
    {
        us8v v = *(const us8v*)src;
        #pragma unroll
        for (int p = 0; p < 8; ++p)
            hrow[o*8+p] = __builtin_bit_cast(float, ((unsigned)v[p]) << 16);
    }
    __syncthreads();
    float acc = linb[o];
    const float* wrow = linw + o*512;
    #pragma unroll 8
    for (int k = 0; k < 512; ++k) acc += hrow[k] * wrow[k];
    out[b*64 + o] = acc;
}

extern "C" void kernel_launch(void* const* d_in, const int* in_sizes, int n_in,
                              void* d_out, int out_size, void* d_ws, size_t ws_size,
                              hipStream_t stream)
{
    const float* x    = (const float*)d_in[0];
    const float* wih0 = (const float*)d_in[1];
    const float* whh0 = (const float*)d_in[2];
    const float* bih0 = (const float*)d_in[3];
    const float* bhh0 = (const float*)d_in[4];
    const float* wih1 = (const float*)d_in[5];
    const float* whh1 = (const float*)d_in[6];
    const float* bih1 = (const float*)d_in[7];
    const float* bih1_ = bih1;  (void)bih1_;
    const float* bhh1 = (const float*)d_in[8];
    const float* linw = (const float*)d_in[9];
    const float* linb = (const float*)d_in[10];
    char* ws = (char*)d_ws;

    // zero both tagged rings + hfin each call (epoch 0 is never expected ->
    // every replay fully re-synchronizes; poison/leftovers can never match)
    (void)hipMemsetAsync(ws + OFF_RING0, 0, 262144u*2 + 65536u, stream);
    hipLaunchKernelGGL(setup_kernel, dim3(1024), dim3(256), 0, stream,
                       x, wih0, whh0, bih0, bhh0, wih1, whh1, bih1, bhh1, ws);
    hipLaunchKernelGGL(lstm_persist, dim3(128), dim3(256), 0, stream, ws);
    hipLaunchKernelGGL(final_linear, dim3(64), dim3(64), 0, stream,
                       ws, linw, linb, (float*)d_out);
}